// Round 8
// baseline (59.173 us; speedup 1.0000x reference)
//
#include <hip/hip_runtime.h>
#include <hip/hip_bf16.h>
#include <cstddef>
#include <cstdint>

// ---------------- constants ----------------
#define BATCH 4096
#define TT 26          // sparse tables
#define LL 4           // lookups per table
#define NROWS 100000
#define MM 64          // embedding dim
#define RSTR 512       // padded R row stride (64 + 351 real + 97 pad)

typedef __attribute__((ext_vector_type(8))) short bf16x8;
typedef __attribute__((ext_vector_type(4))) float f32x4;
typedef __attribute__((ext_vector_type(16))) float f32x16;

#define AS1 __attribute__((address_space(1)))
#define AS3 __attribute__((address_space(3)))

__device__ __forceinline__ void gload_lds16(const void* g, void* l) {
    __builtin_amdgcn_global_load_lds((const AS1 unsigned int*)g,
                                     (AS3 unsigned int*)l, 16, 0, 0);
}

__device__ __forceinline__ float bu2f(unsigned short u) {
    unsigned int x = (unsigned int)u << 16;
    float f; __builtin_memcpy(&f, &x, 4); return f;
}

// ---------------- K1: [gather+partial-gram 0..4095][bot0][conv] ----------------
// gather block b: E[b] (bf16) + T rows 1..26 in LDS; wave0 does Gram over E rows
// (writes Z entries with 1<=col<row); wave1 zeroes R[b][415:512]. Row 0 of T is
// ZERO here; all Z col-0 entries (need x3) are written later by bot2_gram_kernel.
#define GATB 4096
#define BOT0B 8192
__global__ __launch_bounds__(256) void fused_front_kernel(
    const int* __restrict__ idx, const float* __restrict__ emb,
    const float* __restrict__ dense, const float* __restrict__ bw0,
    const float* __restrict__ bb0,
    const float* __restrict__ bw1, const float* __restrict__ bw2,
    const float* __restrict__ tw0, const float* __restrict__ tw1,
    unsigned short* __restrict__ E, __hip_bfloat16* __restrict__ x1,
    __hip_bfloat16* __restrict__ bw1b, __hip_bfloat16* __restrict__ bw2b,
    __hip_bfloat16* __restrict__ tw0b, __hip_bfloat16* __restrict__ tw1b,
    __hip_bfloat16* __restrict__ R)
{
    __shared__ __align__(16) char T[32 * 128];   // 32x64 bf16, XOR-swizzled
    __shared__ int sidx[TT * LL];
    __shared__ float xr[13];
    const int tid = threadIdx.x;

    if (blockIdx.x < GATB) {
        const int b = blockIdx.x;
        const int lane = tid & 63;
        const int w = tid >> 6;
        if (tid < TT * LL) sidx[tid] = idx[(size_t)b * (TT * LL) + tid];
        // zero T rows 0 and 27..31
        for (int i = tid; i < 6 * 64; i += 256) {
            int rid = i >> 6;
            int r = rid ? (26 + rid) : 0;
            int l = i & 63;
            *(short*)(T + r * 128 + ((l * 2) ^ ((r & 7) << 4))) = 0;
        }
        __syncthreads();

        float v[7][4];
#pragma unroll
        for (int rr = 0; rr < 7; rr++) {
            int t = rr * 4 + w;
            if (t < TT) {
                const float* tab = emb + (size_t)t * NROWS * MM + lane;
#pragma unroll
                for (int l = 0; l < LL; l++)
                    v[rr][l] = tab[(size_t)sidx[t * LL + l] * MM];
            }
        }
#pragma unroll
        for (int rr = 0; rr < 7; rr++) {
            int t = rr * 4 + w;
            if (t < TT) {
                float s = v[rr][0] + v[rr][1] + v[rr][2] + v[rr][3];
                __hip_bfloat16 hv = __float2bfloat16(s);
                int r = t + 1;
                *(short*)(T + r * 128 + ((lane * 2) ^ ((r & 7) << 4))) = *(short*)&hv;
                E[(size_t)b * (TT * MM) + t * MM + lane] = *(unsigned short*)&hv;
            }
        }
        __syncthreads();

        __hip_bfloat16* Rb = R + (size_t)b * RSTR;
        if (w == 1) {   // zero pad cols 415..511
            Rb[415 + lane] = __float2bfloat16(0.f);
            if (lane < 33) Rb[479 + lane] = __float2bfloat16(0.f);
        }
        if (w == 0) {   // Gram over T (rows 1..26 live); skip col 0
            f32x16 acc = {};
#pragma unroll
            for (int m = 0; m < 4; m++) {
                int byteoff = (lane & 31) * 128 +
                              ((m * 32 + (lane >> 5) * 16) ^ ((lane & 7) << 4));
                bf16x8 f = *(const bf16x8*)(T + byteoff);
                acc = __builtin_amdgcn_mfma_f32_32x32x16_bf16(f, f, acc, 0, 0, 0);
            }
            const int col = lane & 31;
#pragma unroll
            for (int q = 0; q < 4; q++) {
#pragma unroll
                for (int j = 0; j < 4; j++) {
                    int row = j + 8 * q + 4 * (lane >> 5);
                    if (row < 27 && col >= 1 && col < row)
                        Rb[64 + row * (row - 1) / 2 + col] = __float2bfloat16(acc[q * 4 + j]);
                }
            }
        }
        return;
    }
    if (blockIdx.x < BOT0B) {
        // ---- bottom layer 0 ----
        const int b = blockIdx.x - GATB;
        if (tid < 13) xr[tid] = dense[b * 13 + tid];
        __syncthreads();
        for (int j = tid; j < 512; j += 256) {
            const float* w = bw0 + j * 13;
            float s = bb0[j];
#pragma unroll
            for (int k = 0; k < 13; k++) s = fmaf(xr[k], w[k], s);
            x1[(size_t)b * 512 + j] = __float2bfloat16(fmaxf(s, 0.f));
        }
        return;
    }
    // ---- weight conversion ----
    {
        int i = (blockIdx.x - BOT0B) * 256 + tid;
        if (i < 131072) {
            bw1b[i] = __float2bfloat16(bw1[i]);
        } else if (i < 147456) {
            int j = i - 131072; bw2b[j] = __float2bfloat16(bw2[j]);
        } else if (i < 409600) {
            int j = i - 147456; int n = j >> 9, k = j & 511;
            tw0b[j] = __float2bfloat16(k < 415 ? tw0[n * 415 + k] : 0.f);
        } else if (i < 540672) {
            int j = i - 409600; tw1b[j] = __float2bfloat16(tw1[j]);
        }
    }
}

// ---------------- full-K bf16 MFMA GEMM: C = relu(A @ W^T + bias) (verified R3/R5) ----------------
template<int KK, int ACT>
__global__ __launch_bounds__(256) void gemm_fullk(
    const __hip_bfloat16* __restrict__ A,
    const __hip_bfloat16* __restrict__ W,
    const float* __restrict__ bias,
    __hip_bfloat16* __restrict__ C, int ldc)
{
    constexpr int HS   = KK / 2;
    constexpr int CPRH = KK / 16;
    constexpr int NI   = (64 * CPRH) / 256;
    __shared__ __align__(16) short As0[64 * HS];
    __shared__ __align__(16) short As1[64 * HS];
    __shared__ __align__(16) short Bs0[64 * HS];
    __shared__ __align__(16) short Bs1[64 * HS];

    const int tid  = threadIdx.x;
    const int lane = tid & 63;
    const int wid  = tid >> 6;
    const int wr   = wid >> 1, wc = wid & 1;

    const char* Ab = (const char*)A + (size_t)blockIdx.x * (64 * KK * 2);
    const char* Wb = (const char*)W + (size_t)blockIdx.y * (64 * KK * 2);

    auto stage = [&](const char* Gb, short* Ls, int h) {
#pragma unroll
        for (int j = 0; j < NI; j++) {
            int ci  = j * 256 + tid;
            int row = ci / CPRH;
            int cb  = (ci & (CPRH - 1)) * 16;
            int src = row * (2 * KK) + h * KK + (cb ^ ((row & 7) << 4));
            gload_lds16(Gb + src, (char*)Ls + row * KK + cb);
        }
    };
    stage(Ab, As0, 0); stage(Wb, Bs0, 0);
    stage(Ab, As1, 1); stage(Wb, Bs1, 1);

    const int frow = lane & 15;
    const int fkb  = (lane >> 4) * 16;
    const int xr   = (frow & 7) << 4;
    const int oA0  = (wr * 32 + frow) * KK;
    const int oA1  = oA0 + 16 * KK;
    const int oB0  = (wc * 32 + frow) * KK;
    const int oB1  = oB0 + 16 * KK;

    f32x4 acc[2][2] = {};

    auto compute = [&](const short* Ah, const short* Bh) {
#pragma unroll
        for (int ks = 0; ks < KK / 64; ks++) {
            int pc = (ks * 64 + fkb) ^ xr;
            bf16x8 a0 = *(const bf16x8*)((const char*)Ah + oA0 + pc);
            bf16x8 a1 = *(const bf16x8*)((const char*)Ah + oA1 + pc);
            bf16x8 b0 = *(const bf16x8*)((const char*)Bh + oB0 + pc);
            bf16x8 b1 = *(const bf16x8*)((const char*)Bh + oB1 + pc);
            acc[0][0] = __builtin_amdgcn_mfma_f32_16x16x32_bf16(a0, b0, acc[0][0], 0, 0, 0);
            acc[0][1] = __builtin_amdgcn_mfma_f32_16x16x32_bf16(a0, b1, acc[0][1], 0, 0, 0);
            acc[1][0] = __builtin_amdgcn_mfma_f32_16x16x32_bf16(a1, b0, acc[1][0], 0, 0, 0);
            acc[1][1] = __builtin_amdgcn_mfma_f32_16x16x32_bf16(a1, b1, acc[1][1], 0, 0, 0);
        }
    };

    asm volatile("s_waitcnt vmcnt(%0)" :: "i"(2 * NI) : "memory");
    __builtin_amdgcn_sched_barrier(0);
    __builtin_amdgcn_s_barrier();
    __builtin_amdgcn_sched_barrier(0);
    compute(As0, Bs0);
    asm volatile("s_waitcnt vmcnt(0)" ::: "memory");
    __builtin_amdgcn_sched_barrier(0);
    __builtin_amdgcn_s_barrier();
    __builtin_amdgcn_sched_barrier(0);
    compute(As1, Bs1);

    const int col0 = blockIdx.y * 64 + wc * 32 + (lane & 15);
    const int row0 = blockIdx.x * 64 + wr * 32 + (lane >> 4) * 4;
    float bias_n0 = bias[col0];
    float bias_n1 = bias[col0 + 16];
#pragma unroll
    for (int mi = 0; mi < 2; mi++) {
#pragma unroll
        for (int j = 0; j < 4; j++) {
            int row = row0 + mi * 16 + j;
            float v0 = acc[mi][0][j] + bias_n0;
            float v1 = acc[mi][1][j] + bias_n1;
            if (ACT == 1) { v0 = fmaxf(v0, 0.f); v1 = fmaxf(v1, 0.f); }
            C[(size_t)row * ldc + col0]      = __float2bfloat16(v0);
            C[(size_t)row * ldc + col0 + 16] = __float2bfloat16(v1);
        }
    }
}

// ---------------- K3: bot2 (fullk K=256) + Z col-0 finish ----------------
// Computes x3 = relu(x2@W2^T+b2) -> R[:,0:64] (and LDS); then per batch the
// 26 dots Z[i][0] = E_i . x3 -> R[:, 64 + i(i-1)/2].
__global__ __launch_bounds__(256) void bot2_gram_kernel(
    const __hip_bfloat16* __restrict__ A,
    const __hip_bfloat16* __restrict__ W,
    const float* __restrict__ bias,
    const unsigned short* __restrict__ E,
    __hip_bfloat16* __restrict__ R)
{
    constexpr int KK = 256;
    __shared__ __align__(16) short As0[64 * 128];
    __shared__ __align__(16) short As1[64 * 128];
    __shared__ __align__(16) short Bs0[64 * 128];
    __shared__ __align__(16) short Bs1[64 * 128];
    __shared__ unsigned short x3L[64 * 64];

    const int tid  = threadIdx.x;
    const int lane = tid & 63;
    const int wid  = tid >> 6;
    const int wr   = wid >> 1, wc = wid & 1;

    const char* Ab = (const char*)A + (size_t)blockIdx.x * (64 * KK * 2);
    const char* Wb = (const char*)W;

    auto stage = [&](const char* Gb, short* Ls, int h) {
#pragma unroll
        for (int j = 0; j < 4; j++) {
            int ci  = j * 256 + tid;
            int row = ci >> 4;
            int cb  = (ci & 15) * 16;
            int src = row * (2 * KK) + h * KK + (cb ^ ((row & 7) << 4));
            gload_lds16(Gb + src, (char*)Ls + row * KK + cb);
        }
    };
    stage(Ab, As0, 0); stage(Wb, Bs0, 0);
    stage(Ab, As1, 1); stage(Wb, Bs1, 1);

    const int frow = lane & 15;
    const int fkb  = (lane >> 4) * 16;
    const int xr   = (frow & 7) << 4;
    const int oA0  = (wr * 32 + frow) * KK;
    const int oA1  = oA0 + 16 * KK;
    const int oB0  = (wc * 32 + frow) * KK;
    const int oB1  = oB0 + 16 * KK;

    f32x4 acc[2][2] = {};
    auto compute = [&](const short* Ah, const short* Bh) {
#pragma unroll
        for (int ks = 0; ks < KK / 64; ks++) {
            int pc = (ks * 64 + fkb) ^ xr;
            bf16x8 a0 = *(const bf16x8*)((const char*)Ah + oA0 + pc);
            bf16x8 a1 = *(const bf16x8*)((const char*)Ah + oA1 + pc);
            bf16x8 b0 = *(const bf16x8*)((const char*)Bh + oB0 + pc);
            bf16x8 b1 = *(const bf16x8*)((const char*)Bh + oB1 + pc);
            acc[0][0] = __builtin_amdgcn_mfma_f32_16x16x32_bf16(a0, b0, acc[0][0], 0, 0, 0);
            acc[0][1] = __builtin_amdgcn_mfma_f32_16x16x32_bf16(a0, b1, acc[0][1], 0, 0, 0);
            acc[1][0] = __builtin_amdgcn_mfma_f32_16x16x32_bf16(a1, b0, acc[1][0], 0, 0, 0);
            acc[1][1] = __builtin_amdgcn_mfma_f32_16x16x32_bf16(a1, b1, acc[1][1], 0, 0, 0);
        }
    };

    asm volatile("s_waitcnt vmcnt(8)" ::: "memory");
    __builtin_amdgcn_sched_barrier(0);
    __builtin_amdgcn_s_barrier();
    __builtin_amdgcn_sched_barrier(0);
    compute(As0, Bs0);
    asm volatile("s_waitcnt vmcnt(0)" ::: "memory");
    __builtin_amdgcn_sched_barrier(0);
    __builtin_amdgcn_s_barrier();
    __builtin_amdgcn_sched_barrier(0);
    compute(As1, Bs1);

    const int col0 = wc * 32 + (lane & 15);
    const int lrow0 = wr * 32 + (lane >> 4) * 4;
    const int row0 = blockIdx.x * 64 + lrow0;
    float bias_n0 = bias[col0];
    float bias_n1 = bias[col0 + 16];
#pragma unroll
    for (int mi = 0; mi < 2; mi++) {
#pragma unroll
        for (int j = 0; j < 4; j++) {
            int row = row0 + mi * 16 + j;
            int lr  = lrow0 + mi * 16 + j;
            float v0 = fmaxf(acc[mi][0][j] + bias_n0, 0.f);
            float v1 = fmaxf(acc[mi][1][j] + bias_n1, 0.f);
            __hip_bfloat16 h0 = __float2bfloat16(v0);
            __hip_bfloat16 h1 = __float2bfloat16(v1);
            R[(size_t)row * RSTR + col0]      = h0;
            R[(size_t)row * RSTR + col0 + 16] = h1;
            x3L[lr * 64 + col0]      = *(unsigned short*)&h0;
            x3L[lr * 64 + col0 + 16] = *(unsigned short*)&h1;
        }
    }
    __syncthreads();

    // Z col-0: 64 batches x 26 rows = 1664 dot-64 jobs
    const int b0 = blockIdx.x * 64;
#pragma unroll
    for (int k = 0; k < 7; k++) {
        int job = tid + k * 256;
        if (job < 1664) {
            int bl = job / 26;
            int i  = job - bl * 26 + 1;             // Z row 1..26
            const unsigned short* Er = E + ((size_t)(b0 + bl) * TT + (i - 1)) * MM;
            const unsigned short* xrow = &x3L[bl * 64];
            float s = 0.f;
#pragma unroll
            for (int c = 0; c < 64; c += 4) {
                ushort4 e4 = *(const ushort4*)&Er[c];
                ushort4 x4 = *(const ushort4*)&xrow[c];
                s += bu2f(e4.x) * bu2f(x4.x) + bu2f(e4.y) * bu2f(x4.y)
                   + bu2f(e4.z) * bu2f(x4.z) + bu2f(e4.w) * bu2f(x4.w);
            }
            R[(size_t)(b0 + bl) * RSTR + 64 + i * (i - 1) / 2] = __float2bfloat16(s);
        }
    }
}

// ---------------- double-buffered GEMM (BK=128, 2 blocks/CU) — for top0 (verified R7) ----------------
template<int KK, int ACT>
__global__ __launch_bounds__(256, 2) void gemm_db(
    const __hip_bfloat16* __restrict__ A,
    const __hip_bfloat16* __restrict__ W,
    const float* __restrict__ bias,
    __hip_bfloat16* __restrict__ C, int ldc)
{
    constexpr int KSTEPS = KK / 128;
    __shared__ __align__(16) short As[2][64 * 128];
    __shared__ __align__(16) short Bs[2][64 * 128];

    const int tid  = threadIdx.x;
    const int lane = tid & 63;
    const int wid  = tid >> 6;
    const int wr   = wid >> 1, wc = wid & 1;

    const char* Ab = (const char*)A + (size_t)blockIdx.x * (64 * KK * 2);
    const char* Wb = (const char*)W + (size_t)blockIdx.y * (64 * KK * 2);

    auto stage = [&](const char* Gb, char* Ls, int ks) {
#pragma unroll
        for (int j = 0; j < 4; j++) {
            int ci  = j * 256 + tid;
            int row = ci >> 4;
            int cb  = (ci & 15) * 16;
            int src = row * (2 * KK) + ks * 256 + (cb ^ ((row & 7) << 4));
            gload_lds16(Gb + src, Ls + row * 256 + cb);
        }
    };

    const int fr  = lane & 15;
    const int fkb = (lane >> 4) * 16;
    const int xrr = (fr & 7) << 4;
    const int oA0 = (wr * 32 + fr) * 256;
    const int oA1 = oA0 + 16 * 256;
    const int oB0 = (wc * 32 + fr) * 256;
    const int oB1 = oB0 + 16 * 256;

    f32x4 acc[2][2] = {};

    auto compute = [&](const char* Ah, const char* Bh) {
#pragma unroll
        for (int kf = 0; kf < 4; kf++) {
            int pc = (kf * 64 + fkb) ^ xrr;
            bf16x8 a0 = *(const bf16x8*)(Ah + oA0 + pc);
            bf16x8 a1 = *(const bf16x8*)(Ah + oA1 + pc);
            bf16x8 b0 = *(const bf16x8*)(Bh + oB0 + pc);
            bf16x8 b1 = *(const bf16x8*)(Bh + oB1 + pc);
            acc[0][0] = __builtin_amdgcn_mfma_f32_16x16x32_bf16(a0, b0, acc[0][0], 0, 0, 0);
            acc[0][1] = __builtin_amdgcn_mfma_f32_16x16x32_bf16(a0, b1, acc[0][1], 0, 0, 0);
            acc[1][0] = __builtin_amdgcn_mfma_f32_16x16x32_bf16(a1, b0, acc[1][0], 0, 0, 0);
            acc[1][1] = __builtin_amdgcn_mfma_f32_16x16x32_bf16(a1, b1, acc[1][1], 0, 0, 0);
        }
    };

    stage(Ab, (char*)As[0], 0); stage(Wb, (char*)Bs[0], 0);
    stage(Ab, (char*)As[1], 1); stage(Wb, (char*)Bs[1], 1);

#pragma unroll
    for (int ks = 0; ks < KSTEPS; ks++) {
        if (ks < KSTEPS - 1) { asm volatile("s_waitcnt vmcnt(8)" ::: "memory"); }
        else                 { asm volatile("s_waitcnt vmcnt(0)" ::: "memory"); }
        __builtin_amdgcn_sched_barrier(0);
        __builtin_amdgcn_s_barrier();
        __builtin_amdgcn_sched_barrier(0);
        compute((const char*)As[ks & 1], (const char*)Bs[ks & 1]);
        __builtin_amdgcn_sched_barrier(0);
        if (ks + 2 < KSTEPS) {
            __builtin_amdgcn_s_barrier();
            stage(Ab, (char*)As[ks & 1], ks + 2);
            stage(Wb, (char*)Bs[ks & 1], ks + 2);
        }
    }

    const int col0 = blockIdx.y * 64 + wc * 32 + (lane & 15);
    const int row0 = blockIdx.x * 64 + wr * 32 + (lane >> 4) * 4;
    float bias_n0 = bias[col0];
    float bias_n1 = bias[col0 + 16];
#pragma unroll
    for (int mi = 0; mi < 2; mi++) {
#pragma unroll
        for (int j = 0; j < 4; j++) {
            int row = row0 + mi * 16 + j;
            float v0 = acc[mi][0][j] + bias_n0;
            float v1 = acc[mi][1][j] + bias_n1;
            if (ACT == 1) { v0 = fmaxf(v0, 0.f); v1 = fmaxf(v1, 0.f); }
            C[(size_t)row * ldc + col0]      = __float2bfloat16(v0);
            C[(size_t)row * ldc + col0 + 16] = __float2bfloat16(v1);
        }
    }
}

// ---------------- top layer 2: (4096,256) bf16 -> (4096,1), sigmoid ----------------
__global__ __launch_bounds__(256) void top2_kernel(
    const __hip_bfloat16* __restrict__ h, const float* __restrict__ W,
    const float* __restrict__ bias, float* __restrict__ out)
{
    __shared__ float ws[256];
    int tid = threadIdx.x;
    ws[tid] = W[tid];
    __syncthreads();
    int b = blockIdx.x * 4 + (tid >> 6);
    int lane = tid & 63;
    const unsigned short* hb = (const unsigned short*)(h + (size_t)b * 256);
    ushort4 hv = *(const ushort4*)&hb[lane * 4];
    float4 wv = *(const float4*)&ws[lane * 4];
    float s = bu2f(hv.x) * wv.x + bu2f(hv.y) * wv.y + bu2f(hv.z) * wv.z + bu2f(hv.w) * wv.w;
#pragma unroll
    for (int off = 32; off >= 1; off >>= 1)
        s += __shfl_xor(s, off, 64);
    if (lane == 0) {
        float v = s + bias[0];
        out[b] = 1.0f / (1.0f + expf(-v));
    }
}

// ---------------- launch ----------------
extern "C" void kernel_launch(void* const* d_in, const int* in_sizes, int n_in,
                              void* d_out, int out_size, void* d_ws, size_t ws_size,
                              hipStream_t stream) {
    const float* dense = (const float*)d_in[0];
    const int*   sidx  = (const int*)d_in[1];
    const float* emb   = (const float*)d_in[2];
    const float* bw0   = (const float*)d_in[3];
    const float* bb0   = (const float*)d_in[4];
    const float* bw1   = (const float*)d_in[5];
    const float* bb1   = (const float*)d_in[6];
    const float* bw2   = (const float*)d_in[7];
    const float* bb2   = (const float*)d_in[8];
    const float* tw0   = (const float*)d_in[9];
    const float* tb0   = (const float*)d_in[10];
    const float* tw1   = (const float*)d_in[11];
    const float* tb1   = (const float*)d_in[12];
    const float* tw2   = (const float*)d_in[13];
    const float* tb2   = (const float*)d_in[14];
    float* out = (float*)d_out;

    char* wsb = (char*)d_ws;
    unsigned short* E    = (unsigned short*)(wsb);                 // 4096x26x64 bf16 (13 MiB)
    __hip_bfloat16* R    = (__hip_bfloat16*)(wsb + (16u << 20));   // 4096x512
    __hip_bfloat16* h1   = (__hip_bfloat16*)(wsb + (20u << 20));   // 4096x512
    __hip_bfloat16* h2   = (__hip_bfloat16*)(wsb + (24u << 20));   // 4096x256
    __hip_bfloat16* x1   = (__hip_bfloat16*)(wsb + (26u << 20));   // 4096x512
    __hip_bfloat16* x2   = (__hip_bfloat16*)(wsb + (30u << 20));   // 4096x256
    __hip_bfloat16* bw1b = (__hip_bfloat16*)(wsb + (32u << 20));   // 256x512
    __hip_bfloat16* bw2b = bw1b + 131072;                          // 64x256
    __hip_bfloat16* tw0b = bw2b + 16384;                           // 512x512
    __hip_bfloat16* tw1b = tw0b + 262144;                          // 256x512

    // K1: [gather -> E + partial Gram -> R][bot0 -> x1][weight conversion]
    fused_front_kernel<<<GATB + BATCH + 2112, 256, 0, stream>>>(
        sidx, emb, dense, bw0, bb0, bw1, bw2, tw0, tw1,
        E, x1, bw1b, bw2b, tw0b, tw1b, R);

    // K2: bottom layer 1: x1 (4096,512) -> x2 (4096,256)
    gemm_fullk<512, 1><<<dim3(64, 4), 256, 0, stream>>>(x1, bw1b, bb1, x2, 256);

    // K3: bot2 -> R[:,0:64] + Z col-0 dots
    bot2_gram_kernel<<<64, 256, 0, stream>>>(x2, bw2b, bb2, E, R);

    // K4: top layer 0: R (4096,512) -> h1 (4096,512)  [512 blocks, 2/CU]
    gemm_db<512, 1><<<dim3(64, 8), 256, 0, stream>>>(R, tw0b, tb0, h1, 512);

    // K5: top layer 1: h1 (4096,512) -> h2 (4096,256)
    gemm_fullk<512, 1><<<dim3(64, 4), 256, 0, stream>>>(h1, tw1b, tb1, h2, 256);

    // K6: top layer 2: h2 -> out, sigmoid
    top2_kernel<<<BATCH / 4, 256, 0, stream>>>(h2, tw2, tb2, out);
}

// Round 9
// 56.000 us; speedup vs baseline: 1.0567x; 1.0567x over previous
//
#include <hip/hip_runtime.h>
#include <hip/hip_bf16.h>
#include <cstddef>
#include <cstdint>

// ---------------- constants ----------------
#define BATCH 4096
#define TT 26          // sparse tables
#define LL 4           // lookups per table
#define NROWS 100000
#define MM 64          // embedding dim
#define RSTR 512       // padded R row stride (64 + 351 real + 97 pad)

typedef __attribute__((ext_vector_type(8))) short bf16x8;
typedef __attribute__((ext_vector_type(4))) float f32x4;
typedef __attribute__((ext_vector_type(16))) float f32x16;

#define AS1 __attribute__((address_space(1)))
#define AS3 __attribute__((address_space(3)))

__device__ __forceinline__ void gload_lds16(const void* g, void* l) {
    __builtin_amdgcn_global_load_lds((const AS1 unsigned int*)g,
                                     (AS3 unsigned int*)l, 16, 0, 0);
}

__device__ __forceinline__ float bu2f(unsigned short u) {
    unsigned int x = (unsigned int)u << 16;
    float f; __builtin_memcpy(&f, &x, 4); return f;
}

// ---------------- K1: [gather 0..4095][bot0 4096..8191][conv 8192..10303] ----------------
// gather: E[b][t][:] = bf16(sum of 4 rows). bot0: x1 = relu(dense@W0^T+b0).
// conv: bw1b(256,512) bw2b(64,256) tw0b(512,512 pad from 415) tw1b(256,512).
#define GATB 4096
#define BOT0B 8192
__global__ __launch_bounds__(256) void fused_front_kernel(
    const int* __restrict__ idx, const float* __restrict__ emb,
    const float* __restrict__ dense, const float* __restrict__ bw0,
    const float* __restrict__ bb0,
    const float* __restrict__ bw1, const float* __restrict__ bw2,
    const float* __restrict__ tw0, const float* __restrict__ tw1,
    unsigned short* __restrict__ E, __hip_bfloat16* __restrict__ x1,
    __hip_bfloat16* __restrict__ bw1b, __hip_bfloat16* __restrict__ bw2b,
    __hip_bfloat16* __restrict__ tw0b, __hip_bfloat16* __restrict__ tw1b)
{
    __shared__ int sidx[TT * LL];
    __shared__ float xr[13];
    const int tid = threadIdx.x;

    if (blockIdx.x < GATB) {
        // ---- embedding gather (latency-bound; dispatched first, fills machine) ----
        const int b = blockIdx.x;
        const int lane = tid & 63;
        const int w = tid >> 6;
        if (tid < TT * LL) sidx[tid] = idx[(size_t)b * (TT * LL) + tid];
        __syncthreads();
        float v[7][4];
#pragma unroll
        for (int rr = 0; rr < 7; rr++) {
            int t = rr * 4 + w;
            if (t < TT) {
                const float* tab = emb + (size_t)t * NROWS * MM + lane;
#pragma unroll
                for (int l = 0; l < LL; l++)
                    v[rr][l] = tab[(size_t)sidx[t * LL + l] * MM];
            }
        }
#pragma unroll
        for (int rr = 0; rr < 7; rr++) {
            int t = rr * 4 + w;
            if (t < TT) {
                float s = v[rr][0] + v[rr][1] + v[rr][2] + v[rr][3];
                __hip_bfloat16 hv = __float2bfloat16(s);
                E[(size_t)b * (TT * MM) + t * MM + lane] = *(unsigned short*)&hv;
            }
        }
        return;
    }
    if (blockIdx.x < BOT0B) {
        // ---- bottom layer 0 ----
        const int b = blockIdx.x - GATB;
        if (tid < 13) xr[tid] = dense[b * 13 + tid];
        __syncthreads();
        for (int j = tid; j < 512; j += 256) {
            const float* w = bw0 + j * 13;
            float s = bb0[j];
#pragma unroll
            for (int k = 0; k < 13; k++) s = fmaf(xr[k], w[k], s);
            x1[(size_t)b * 512 + j] = __float2bfloat16(fmaxf(s, 0.f));
        }
        return;
    }
    // ---- weight conversion ----
    {
        int i = (blockIdx.x - BOT0B) * 256 + tid;
        if (i < 131072) {
            bw1b[i] = __float2bfloat16(bw1[i]);
        } else if (i < 147456) {
            int j = i - 131072; bw2b[j] = __float2bfloat16(bw2[j]);
        } else if (i < 409600) {
            int j = i - 147456; int n = j >> 9, k = j & 511;
            tw0b[j] = __float2bfloat16(k < 415 ? tw0[n * 415 + k] : 0.f);
        } else if (i < 540672) {
            int j = i - 409600; tw1b[j] = __float2bfloat16(tw1[j]);
        }
    }
}

// ---------------- full-K bf16 MFMA GEMM: C = relu(A @ W^T + bias) (verified R3/R5) ----------------
// Deep-prefetch variant: entire K panel staged (32 loads in flight/thread).
// Best for grids <= 256 blocks (1 block/CU regardless of LDS).
template<int KK, int ACT>
__global__ __launch_bounds__(256) void gemm_fullk(
    const __hip_bfloat16* __restrict__ A,
    const __hip_bfloat16* __restrict__ W,
    const float* __restrict__ bias,
    __hip_bfloat16* __restrict__ C, int ldc)
{
    constexpr int HS   = KK / 2;
    constexpr int CPRH = KK / 16;
    constexpr int NI   = (64 * CPRH) / 256;
    __shared__ __align__(16) short As0[64 * HS];
    __shared__ __align__(16) short As1[64 * HS];
    __shared__ __align__(16) short Bs0[64 * HS];
    __shared__ __align__(16) short Bs1[64 * HS];

    const int tid  = threadIdx.x;
    const int lane = tid & 63;
    const int wid  = tid >> 6;
    const int wr   = wid >> 1, wc = wid & 1;

    const char* Ab = (const char*)A + (size_t)blockIdx.x * (64 * KK * 2);
    const char* Wb = (const char*)W + (size_t)blockIdx.y * (64 * KK * 2);

    auto stage = [&](const char* Gb, short* Ls, int h) {
#pragma unroll
        for (int j = 0; j < NI; j++) {
            int ci  = j * 256 + tid;
            int row = ci / CPRH;
            int cb  = (ci & (CPRH - 1)) * 16;
            int src = row * (2 * KK) + h * KK + (cb ^ ((row & 7) << 4));
            gload_lds16(Gb + src, (char*)Ls + row * KK + cb);
        }
    };
    stage(Ab, As0, 0); stage(Wb, Bs0, 0);
    stage(Ab, As1, 1); stage(Wb, Bs1, 1);

    const int frow = lane & 15;
    const int fkb  = (lane >> 4) * 16;
    const int xr   = (frow & 7) << 4;
    const int oA0  = (wr * 32 + frow) * KK;
    const int oA1  = oA0 + 16 * KK;
    const int oB0  = (wc * 32 + frow) * KK;
    const int oB1  = oB0 + 16 * KK;

    f32x4 acc[2][2] = {};

    auto compute = [&](const short* Ah, const short* Bh) {
#pragma unroll
        for (int ks = 0; ks < KK / 64; ks++) {
            int pc = (ks * 64 + fkb) ^ xr;
            bf16x8 a0 = *(const bf16x8*)((const char*)Ah + oA0 + pc);
            bf16x8 a1 = *(const bf16x8*)((const char*)Ah + oA1 + pc);
            bf16x8 b0 = *(const bf16x8*)((const char*)Bh + oB0 + pc);
            bf16x8 b1 = *(const bf16x8*)((const char*)Bh + oB1 + pc);
            acc[0][0] = __builtin_amdgcn_mfma_f32_16x16x32_bf16(a0, b0, acc[0][0], 0, 0, 0);
            acc[0][1] = __builtin_amdgcn_mfma_f32_16x16x32_bf16(a0, b1, acc[0][1], 0, 0, 0);
            acc[1][0] = __builtin_amdgcn_mfma_f32_16x16x32_bf16(a1, b0, acc[1][0], 0, 0, 0);
            acc[1][1] = __builtin_amdgcn_mfma_f32_16x16x32_bf16(a1, b1, acc[1][1], 0, 0, 0);
        }
    };

    asm volatile("s_waitcnt vmcnt(%0)" :: "i"(2 * NI) : "memory");
    __builtin_amdgcn_sched_barrier(0);
    __builtin_amdgcn_s_barrier();
    __builtin_amdgcn_sched_barrier(0);
    compute(As0, Bs0);
    asm volatile("s_waitcnt vmcnt(0)" ::: "memory");
    __builtin_amdgcn_sched_barrier(0);
    __builtin_amdgcn_s_barrier();
    __builtin_amdgcn_sched_barrier(0);
    compute(As1, Bs1);

    const int col0 = blockIdx.y * 64 + wc * 32 + (lane & 15);
    const int row0 = blockIdx.x * 64 + wr * 32 + (lane >> 4) * 4;
    float bias_n0 = bias[col0];
    float bias_n1 = bias[col0 + 16];
#pragma unroll
    for (int mi = 0; mi < 2; mi++) {
#pragma unroll
        for (int j = 0; j < 4; j++) {
            int row = row0 + mi * 16 + j;
            float v0 = acc[mi][0][j] + bias_n0;
            float v1 = acc[mi][1][j] + bias_n1;
            if (ACT == 1) { v0 = fmaxf(v0, 0.f); v1 = fmaxf(v1, 0.f); }
            C[(size_t)row * ldc + col0]      = __float2bfloat16(v0);
            C[(size_t)row * ldc + col0 + 16] = __float2bfloat16(v1);
        }
    }
}

// ---------------- double-buffered GEMM (BK=128, 2 blocks/CU) — for top0 only (verified R7) ----------------
template<int KK, int ACT>
__global__ __launch_bounds__(256, 2) void gemm_db(
    const __hip_bfloat16* __restrict__ A,
    const __hip_bfloat16* __restrict__ W,
    const float* __restrict__ bias,
    __hip_bfloat16* __restrict__ C, int ldc)
{
    constexpr int KSTEPS = KK / 128;
    __shared__ __align__(16) short As[2][64 * 128];
    __shared__ __align__(16) short Bs[2][64 * 128];

    const int tid  = threadIdx.x;
    const int lane = tid & 63;
    const int wid  = tid >> 6;
    const int wr   = wid >> 1, wc = wid & 1;

    const char* Ab = (const char*)A + (size_t)blockIdx.x * (64 * KK * 2);
    const char* Wb = (const char*)W + (size_t)blockIdx.y * (64 * KK * 2);

    auto stage = [&](const char* Gb, char* Ls, int ks) {
#pragma unroll
        for (int j = 0; j < 4; j++) {
            int ci  = j * 256 + tid;
            int row = ci >> 4;
            int cb  = (ci & 15) * 16;
            int src = row * (2 * KK) + ks * 256 + (cb ^ ((row & 7) << 4));
            gload_lds16(Gb + src, Ls + row * 256 + cb);
        }
    };

    const int fr  = lane & 15;
    const int fkb = (lane >> 4) * 16;
    const int xrr = (fr & 7) << 4;
    const int oA0 = (wr * 32 + fr) * 256;
    const int oA1 = oA0 + 16 * 256;
    const int oB0 = (wc * 32 + fr) * 256;
    const int oB1 = oB0 + 16 * 256;

    f32x4 acc[2][2] = {};

    auto compute = [&](const char* Ah, const char* Bh) {
#pragma unroll
        for (int kf = 0; kf < 4; kf++) {
            int pc = (kf * 64 + fkb) ^ xrr;
            bf16x8 a0 = *(const bf16x8*)(Ah + oA0 + pc);
            bf16x8 a1 = *(const bf16x8*)(Ah + oA1 + pc);
            bf16x8 b0 = *(const bf16x8*)(Bh + oB0 + pc);
            bf16x8 b1 = *(const bf16x8*)(Bh + oB1 + pc);
            acc[0][0] = __builtin_amdgcn_mfma_f32_16x16x32_bf16(a0, b0, acc[0][0], 0, 0, 0);
            acc[0][1] = __builtin_amdgcn_mfma_f32_16x16x32_bf16(a0, b1, acc[0][1], 0, 0, 0);
            acc[1][0] = __builtin_amdgcn_mfma_f32_16x16x32_bf16(a1, b0, acc[1][0], 0, 0, 0);
            acc[1][1] = __builtin_amdgcn_mfma_f32_16x16x32_bf16(a1, b1, acc[1][1], 0, 0, 0);
        }
    };

    stage(Ab, (char*)As[0], 0); stage(Wb, (char*)Bs[0], 0);
    stage(Ab, (char*)As[1], 1); stage(Wb, (char*)Bs[1], 1);

#pragma unroll
    for (int ks = 0; ks < KSTEPS; ks++) {
        if (ks < KSTEPS - 1) { asm volatile("s_waitcnt vmcnt(8)" ::: "memory"); }
        else                 { asm volatile("s_waitcnt vmcnt(0)" ::: "memory"); }
        __builtin_amdgcn_sched_barrier(0);
        __builtin_amdgcn_s_barrier();
        __builtin_amdgcn_sched_barrier(0);
        compute((const char*)As[ks & 1], (const char*)Bs[ks & 1]);
        __builtin_amdgcn_sched_barrier(0);
        if (ks + 2 < KSTEPS) {
            __builtin_amdgcn_s_barrier();
            stage(Ab, (char*)As[ks & 1], ks + 2);
            stage(Wb, (char*)Bs[ks & 1], ks + 2);
        }
    }

    const int col0 = blockIdx.y * 64 + wc * 32 + (lane & 15);
    const int row0 = blockIdx.x * 64 + wr * 32 + (lane >> 4) * 4;
    float bias_n0 = bias[col0];
    float bias_n1 = bias[col0 + 16];
#pragma unroll
    for (int mi = 0; mi < 2; mi++) {
#pragma unroll
        for (int j = 0; j < 4; j++) {
            int row = row0 + mi * 16 + j;
            float v0 = acc[mi][0][j] + bias_n0;
            float v1 = acc[mi][1][j] + bias_n1;
            if (ACT == 1) { v0 = fmaxf(v0, 0.f); v1 = fmaxf(v1, 0.f); }
            C[(size_t)row * ldc + col0]      = __float2bfloat16(v0);
            C[(size_t)row * ldc + col0 + 16] = __float2bfloat16(v1);
        }
    }
}

// ---------------- interaction (Gram) from E + x3 -> R[:, 64:512] (verified R6/R7) ----------------
// 1024 blocks x 4 waves; wave w owns batch blockIdx.x*4 + w (its own 32x64 T).
__global__ __launch_bounds__(256) void interact_kernel(
    const unsigned short* __restrict__ E, __hip_bfloat16* __restrict__ R)
{
    __shared__ __align__(16) char T[4][32 * 128];   // per-wave 32x64 bf16, swizzled
    const int tid = threadIdx.x;
    const int lane = tid & 63;
    const int w = tid >> 6;
    const int b = blockIdx.x * 4 + w;
    char* Tw = T[w];
    const unsigned short* Eb = E + (size_t)b * (TT * MM);
    const unsigned short* Xb = (const unsigned short*)R + (size_t)b * RSTR;

#pragma unroll
    for (int i = 0; i < 7; i++) {
        int id = i * 64 + lane;
        if (id < 432) {
            int r = id >> 4, c4 = (id & 15) * 4;
            const unsigned short* src = (r == 0) ? (Xb + c4) : (Eb + (r - 1) * 64 + c4);
            ushort4 val = *(const ushort4*)src;
            *(ushort4*)(Tw + r * 128 + ((c4 * 2) ^ ((r & 7) << 4))) = val;
        }
    }
#pragma unroll
    for (int i = 0; i < 2; i++) {
        int id = i * 64 + lane;
        if (id < 80) {
            int r = 27 + (id >> 4), c4 = (id & 15) * 4;
            *(ushort4*)(Tw + r * 128 + ((c4 * 2) ^ ((r & 7) << 4))) = (ushort4){0, 0, 0, 0};
        }
    }
    __syncthreads();

    f32x16 acc = {};
#pragma unroll
    for (int m = 0; m < 4; m++) {
        int byteoff = (lane & 31) * 128 + ((m * 32 + (lane >> 5) * 16) ^ ((lane & 7) << 4));
        bf16x8 f = *(const bf16x8*)(Tw + byteoff);
        acc = __builtin_amdgcn_mfma_f32_32x32x16_bf16(f, f, acc, 0, 0, 0);
    }
    __hip_bfloat16* Rb = R + (size_t)b * RSTR;
    const int col = lane & 31;
#pragma unroll
    for (int q = 0; q < 4; q++) {
#pragma unroll
        for (int j = 0; j < 4; j++) {
            int row = j + 8 * q + 4 * (lane >> 5);
            if (row < 27 && col < row)
                Rb[64 + row * (row - 1) / 2 + col] = __float2bfloat16(acc[q * 4 + j]);
        }
    }
    for (int p = lane; p < 97; p += 64)
        Rb[415 + p] = __float2bfloat16(0.f);
}

// ---------------- top layer 2: (4096,256) bf16 -> (4096,1), sigmoid ----------------
__global__ __launch_bounds__(256) void top2_kernel(
    const __hip_bfloat16* __restrict__ h, const float* __restrict__ W,
    const float* __restrict__ bias, float* __restrict__ out)
{
    __shared__ float ws[256];
    int tid = threadIdx.x;
    ws[tid] = W[tid];
    __syncthreads();
    int b = blockIdx.x * 4 + (tid >> 6);
    int lane = tid & 63;
    const unsigned short* hb = (const unsigned short*)(h + (size_t)b * 256);
    ushort4 hv = *(const ushort4*)&hb[lane * 4];
    float4 wv = *(const float4*)&ws[lane * 4];
    float s = bu2f(hv.x) * wv.x + bu2f(hv.y) * wv.y + bu2f(hv.z) * wv.z + bu2f(hv.w) * wv.w;
#pragma unroll
    for (int off = 32; off >= 1; off >>= 1)
        s += __shfl_xor(s, off, 64);
    if (lane == 0) {
        float v = s + bias[0];
        out[b] = 1.0f / (1.0f + expf(-v));
    }
}

// ---------------- launch ----------------
extern "C" void kernel_launch(void* const* d_in, const int* in_sizes, int n_in,
                              void* d_out, int out_size, void* d_ws, size_t ws_size,
                              hipStream_t stream) {
    const float* dense = (const float*)d_in[0];
    const int*   sidx  = (const int*)d_in[1];
    const float* emb   = (const float*)d_in[2];
    const float* bw0   = (const float*)d_in[3];
    const float* bb0   = (const float*)d_in[4];
    const float* bw1   = (const float*)d_in[5];
    const float* bb1   = (const float*)d_in[6];
    const float* bw2   = (const float*)d_in[7];
    const float* bb2   = (const float*)d_in[8];
    const float* tw0   = (const float*)d_in[9];
    const float* tb0   = (const float*)d_in[10];
    const float* tw1   = (const float*)d_in[11];
    const float* tb1   = (const float*)d_in[12];
    const float* tw2   = (const float*)d_in[13];
    const float* tb2   = (const float*)d_in[14];
    float* out = (float*)d_out;

    char* wsb = (char*)d_ws;
    unsigned short* E    = (unsigned short*)(wsb);                 // 4096x26x64 bf16 (13 MiB)
    __hip_bfloat16* R    = (__hip_bfloat16*)(wsb + (16u << 20));   // 4096x512
    __hip_bfloat16* h1   = (__hip_bfloat16*)(wsb + (20u << 20));   // 4096x512
    __hip_bfloat16* h2   = (__hip_bfloat16*)(wsb + (24u << 20));   // 4096x256
    __hip_bfloat16* x1   = (__hip_bfloat16*)(wsb + (26u << 20));   // 4096x512
    __hip_bfloat16* x2   = (__hip_bfloat16*)(wsb + (30u << 20));   // 4096x256
    __hip_bfloat16* bw1b = (__hip_bfloat16*)(wsb + (32u << 20));   // 256x512
    __hip_bfloat16* bw2b = bw1b + 131072;                          // 64x256
    __hip_bfloat16* tw0b = bw2b + 16384;                           // 512x512
    __hip_bfloat16* tw1b = tw0b + 262144;                          // 256x512

    // K1: [gather -> E][bot0 -> x1][weight conversion] (gather dispatched first)
    fused_front_kernel<<<GATB + BATCH + 2112, 256, 0, stream>>>(
        sidx, emb, dense, bw0, bb0, bw1, bw2, tw0, tw1,
        E, x1, bw1b, bw2b, tw0b, tw1b);

    // K2: bottom layer 1: x1 (4096,512) -> x2 (4096,256)   [256 blocks -> fullk]
    gemm_fullk<512, 1><<<dim3(64, 4), 256, 0, stream>>>(x1, bw1b, bb1, x2, 256);

    // K3: bottom layer 2: x2 (4096,256) -> R[:, 0:64]      [64 blocks -> fullk]
    gemm_fullk<256, 1><<<dim3(64, 1), 256, 0, stream>>>(x2, bw2b, bb2, R, RSTR);

    // K4: interaction -> R[:, 64:512]                      [1024 blocks]
    interact_kernel<<<BATCH / 4, 256, 0, stream>>>(E, R);

    // K5: top layer 0: R (4096,512) -> h1 (4096,512)       [512 blocks -> db, 2/CU]
    gemm_db<512, 1><<<dim3(64, 8), 256, 0, stream>>>(R, tw0b, tb0, h1, 512);

    // K6: top layer 1: h1 (4096,512) -> h2 (4096,256)      [256 blocks -> fullk]
    gemm_fullk<512, 1><<<dim3(64, 4), 256, 0, stream>>>(h1, tw1b, tb1, h2, 256);

    // K7: top layer 2: h2 -> out, sigmoid
    top2_kernel<<<BATCH / 4, 256, 0, stream>>>(h2, tw2, tb2, out);
}

// Round 10
// 53.591 us; speedup vs baseline: 1.1042x; 1.0450x over previous
//
#include <hip/hip_runtime.h>
#include <hip/hip_bf16.h>
#include <cstddef>
#include <cstdint>

// ---------------- constants ----------------
#define BATCH 4096
#define TT 26          // sparse tables
#define LL 4           // lookups per table
#define NROWS 100000
#define MM 64          // embedding dim
#define RSTR 512       // padded R row stride (64 + 351 real + 97 pad)

typedef __attribute__((ext_vector_type(8))) short bf16x8;
typedef __attribute__((ext_vector_type(4))) float f32x4;
typedef __attribute__((ext_vector_type(16))) float f32x16;

#define AS1 __attribute__((address_space(1)))
#define AS3 __attribute__((address_space(3)))

__device__ __forceinline__ void gload_lds16(const void* g, void* l) {
    __builtin_amdgcn_global_load_lds((const AS1 unsigned int*)g,
                                     (AS3 unsigned int*)l, 16, 0, 0);
}

__device__ __forceinline__ float bu2f(unsigned short u) {
    unsigned int x = (unsigned int)u << 16;
    float f; __builtin_memcpy(&f, &x, 4); return f;
}

// ---------------- prep: weight conversion (blocks 0..2111) + bot layer 0 ----------------
#define CONV_BLOCKS 2112
__global__ __launch_bounds__(256) void prep_kernel(
    const float* __restrict__ dense, const float* __restrict__ bw0,
    const float* __restrict__ bb0,
    const float* __restrict__ bw1, const float* __restrict__ bw2,
    const float* __restrict__ tw0, const float* __restrict__ tw1,
    __hip_bfloat16* __restrict__ x1,
    __hip_bfloat16* __restrict__ bw1b, __hip_bfloat16* __restrict__ bw2b,
    __hip_bfloat16* __restrict__ tw0b, __hip_bfloat16* __restrict__ tw1b)
{
    __shared__ float xr[13];
    if (blockIdx.x < CONV_BLOCKS) {
        int i = blockIdx.x * 256 + threadIdx.x;
        if (i < 131072) {
            bw1b[i] = __float2bfloat16(bw1[i]);
        } else if (i < 147456) {
            int j = i - 131072; bw2b[j] = __float2bfloat16(bw2[j]);
        } else if (i < 409600) {
            int j = i - 147456; int n = j >> 9, k = j & 511;
            tw0b[j] = __float2bfloat16(k < 415 ? tw0[n * 415 + k] : 0.f);
        } else {
            int j = i - 409600; tw1b[j] = __float2bfloat16(tw1[j]);
        }
        return;
    }
    int b = blockIdx.x - CONV_BLOCKS;
    if (threadIdx.x < 13) xr[threadIdx.x] = dense[b * 13 + threadIdx.x];
    __syncthreads();
    for (int j = threadIdx.x; j < 512; j += 256) {
        const float* w = bw0 + j * 13;
        float s = bb0[j];
#pragma unroll
        for (int k = 0; k < 13; k++) s = fmaf(xr[k], w[k], s);
        x1[(size_t)b * 512 + j] = __float2bfloat16(fmaxf(s, 0.f));
    }
}

// ---------------- full-K bf16 MFMA GEMM: C = relu(A @ W^T + bias) (verified R3/R5) ----------------
// Deep prefetch (whole K panel, 32 loads in flight); best for grids <= 256 blocks.
template<int KK, int ACT>
__global__ __launch_bounds__(256) void gemm_fullk(
    const __hip_bfloat16* __restrict__ A,
    const __hip_bfloat16* __restrict__ W,
    const float* __restrict__ bias,
    __hip_bfloat16* __restrict__ C, int ldc)
{
    constexpr int HS   = KK / 2;
    constexpr int CPRH = KK / 16;
    constexpr int NI   = (64 * CPRH) / 256;
    __shared__ __align__(16) short As0[64 * HS];
    __shared__ __align__(16) short As1[64 * HS];
    __shared__ __align__(16) short Bs0[64 * HS];
    __shared__ __align__(16) short Bs1[64 * HS];

    const int tid  = threadIdx.x;
    const int lane = tid & 63;
    const int wid  = tid >> 6;
    const int wr   = wid >> 1, wc = wid & 1;

    const char* Ab = (const char*)A + (size_t)blockIdx.x * (64 * KK * 2);
    const char* Wb = (const char*)W + (size_t)blockIdx.y * (64 * KK * 2);

    auto stage = [&](const char* Gb, short* Ls, int h) {
#pragma unroll
        for (int j = 0; j < NI; j++) {
            int ci  = j * 256 + tid;
            int row = ci / CPRH;
            int cb  = (ci & (CPRH - 1)) * 16;
            int src = row * (2 * KK) + h * KK + (cb ^ ((row & 7) << 4));
            gload_lds16(Gb + src, (char*)Ls + row * KK + cb);
        }
    };
    stage(Ab, As0, 0); stage(Wb, Bs0, 0);
    stage(Ab, As1, 1); stage(Wb, Bs1, 1);

    const int frow = lane & 15;
    const int fkb  = (lane >> 4) * 16;
    const int xr   = (frow & 7) << 4;
    const int oA0  = (wr * 32 + frow) * KK;
    const int oA1  = oA0 + 16 * KK;
    const int oB0  = (wc * 32 + frow) * KK;
    const int oB1  = oB0 + 16 * KK;

    f32x4 acc[2][2] = {};

    auto compute = [&](const short* Ah, const short* Bh) {
#pragma unroll
        for (int ks = 0; ks < KK / 64; ks++) {
            int pc = (ks * 64 + fkb) ^ xr;
            bf16x8 a0 = *(const bf16x8*)((const char*)Ah + oA0 + pc);
            bf16x8 a1 = *(const bf16x8*)((const char*)Ah + oA1 + pc);
            bf16x8 b0 = *(const bf16x8*)((const char*)Bh + oB0 + pc);
            bf16x8 b1 = *(const bf16x8*)((const char*)Bh + oB1 + pc);
            acc[0][0] = __builtin_amdgcn_mfma_f32_16x16x32_bf16(a0, b0, acc[0][0], 0, 0, 0);
            acc[0][1] = __builtin_amdgcn_mfma_f32_16x16x32_bf16(a0, b1, acc[0][1], 0, 0, 0);
            acc[1][0] = __builtin_amdgcn_mfma_f32_16x16x32_bf16(a1, b0, acc[1][0], 0, 0, 0);
            acc[1][1] = __builtin_amdgcn_mfma_f32_16x16x32_bf16(a1, b1, acc[1][1], 0, 0, 0);
        }
    };

    asm volatile("s_waitcnt vmcnt(%0)" :: "i"(2 * NI) : "memory");
    __builtin_amdgcn_sched_barrier(0);
    __builtin_amdgcn_s_barrier();
    __builtin_amdgcn_sched_barrier(0);
    compute(As0, Bs0);
    asm volatile("s_waitcnt vmcnt(0)" ::: "memory");
    __builtin_amdgcn_sched_barrier(0);
    __builtin_amdgcn_s_barrier();
    __builtin_amdgcn_sched_barrier(0);
    compute(As1, Bs1);

    const int col0 = blockIdx.y * 64 + wc * 32 + (lane & 15);
    const int row0 = blockIdx.x * 64 + wr * 32 + (lane >> 4) * 4;
    float bias_n0 = bias[col0];
    float bias_n1 = bias[col0 + 16];
#pragma unroll
    for (int mi = 0; mi < 2; mi++) {
#pragma unroll
        for (int j = 0; j < 4; j++) {
            int row = row0 + mi * 16 + j;
            float v0 = acc[mi][0][j] + bias_n0;
            float v1 = acc[mi][1][j] + bias_n1;
            if (ACT == 1) { v0 = fmaxf(v0, 0.f); v1 = fmaxf(v1, 0.f); }
            C[(size_t)row * ldc + col0]      = __float2bfloat16(v0);
            C[(size_t)row * ldc + col0 + 16] = __float2bfloat16(v1);
        }
    }
}

// ---------------- double-buffered GEMM (BK=128, 2 blocks/CU) — top0 only (verified R7/R9) ----------------
template<int KK, int ACT>
__global__ __launch_bounds__(256, 2) void gemm_db(
    const __hip_bfloat16* __restrict__ A,
    const __hip_bfloat16* __restrict__ W,
    const float* __restrict__ bias,
    __hip_bfloat16* __restrict__ C, int ldc)
{
    constexpr int KSTEPS = KK / 128;
    __shared__ __align__(16) short As[2][64 * 128];
    __shared__ __align__(16) short Bs[2][64 * 128];

    const int tid  = threadIdx.x;
    const int lane = tid & 63;
    const int wid  = tid >> 6;
    const int wr   = wid >> 1, wc = wid & 1;

    const char* Ab = (const char*)A + (size_t)blockIdx.x * (64 * KK * 2);
    const char* Wb = (const char*)W + (size_t)blockIdx.y * (64 * KK * 2);

    auto stage = [&](const char* Gb, char* Ls, int ks) {
#pragma unroll
        for (int j = 0; j < 4; j++) {
            int ci  = j * 256 + tid;
            int row = ci >> 4;
            int cb  = (ci & 15) * 16;
            int src = row * (2 * KK) + ks * 256 + (cb ^ ((row & 7) << 4));
            gload_lds16(Gb + src, Ls + row * 256 + cb);
        }
    };

    const int fr  = lane & 15;
    const int fkb = (lane >> 4) * 16;
    const int xrr = (fr & 7) << 4;
    const int oA0 = (wr * 32 + fr) * 256;
    const int oA1 = oA0 + 16 * 256;
    const int oB0 = (wc * 32 + fr) * 256;
    const int oB1 = oB0 + 16 * 256;

    f32x4 acc[2][2] = {};

    auto compute = [&](const char* Ah, const char* Bh) {
#pragma unroll
        for (int kf = 0; kf < 4; kf++) {
            int pc = (kf * 64 + fkb) ^ xrr;
            bf16x8 a0 = *(const bf16x8*)(Ah + oA0 + pc);
            bf16x8 a1 = *(const bf16x8*)(Ah + oA1 + pc);
            bf16x8 b0 = *(const bf16x8*)(Bh + oB0 + pc);
            bf16x8 b1 = *(const bf16x8*)(Bh + oB1 + pc);
            acc[0][0] = __builtin_amdgcn_mfma_f32_16x16x32_bf16(a0, b0, acc[0][0], 0, 0, 0);
            acc[0][1] = __builtin_amdgcn_mfma_f32_16x16x32_bf16(a0, b1, acc[0][1], 0, 0, 0);
            acc[1][0] = __builtin_amdgcn_mfma_f32_16x16x32_bf16(a1, b0, acc[1][0], 0, 0, 0);
            acc[1][1] = __builtin_amdgcn_mfma_f32_16x16x32_bf16(a1, b1, acc[1][1], 0, 0, 0);
        }
    };

    stage(Ab, (char*)As[0], 0); stage(Wb, (char*)Bs[0], 0);
    stage(Ab, (char*)As[1], 1); stage(Wb, (char*)Bs[1], 1);

#pragma unroll
    for (int ks = 0; ks < KSTEPS; ks++) {
        if (ks < KSTEPS - 1) { asm volatile("s_waitcnt vmcnt(8)" ::: "memory"); }
        else                 { asm volatile("s_waitcnt vmcnt(0)" ::: "memory"); }
        __builtin_amdgcn_sched_barrier(0);
        __builtin_amdgcn_s_barrier();
        __builtin_amdgcn_sched_barrier(0);
        compute((const char*)As[ks & 1], (const char*)Bs[ks & 1]);
        __builtin_amdgcn_sched_barrier(0);
        if (ks + 2 < KSTEPS) {
            __builtin_amdgcn_s_barrier();
            stage(Ab, (char*)As[ks & 1], ks + 2);
            stage(Wb, (char*)Bs[ks & 1], ks + 2);
        }
    }

    const int col0 = blockIdx.y * 64 + wc * 32 + (lane & 15);
    const int row0 = blockIdx.x * 64 + wr * 32 + (lane >> 4) * 4;
    float bias_n0 = bias[col0];
    float bias_n1 = bias[col0 + 16];
#pragma unroll
    for (int mi = 0; mi < 2; mi++) {
#pragma unroll
        for (int j = 0; j < 4; j++) {
            int row = row0 + mi * 16 + j;
            float v0 = acc[mi][0][j] + bias_n0;
            float v1 = acc[mi][1][j] + bias_n1;
            if (ACT == 1) { v0 = fmaxf(v0, 0.f); v1 = fmaxf(v1, 0.f); }
            C[(size_t)row * ldc + col0]      = __float2bfloat16(v0);
            C[(size_t)row * ldc + col0 + 16] = __float2bfloat16(v1);
        }
    }
}

// ---------------- fused embedding gather + MFMA-Gram interaction (verified R5) ----------------
// 1 batch per block, 4 waves. Gather: wave w loads rows r = rr*4+w (row 0 = x3
// from R, written by bot2). Rows stored bf16 into XOR-swizzled T (32x64).
// Gram: wave 0 computes T·T^T via 4x mfma_32x32x16_bf16 (A-frag == B-frag),
// writes lower-triangle to R[:, 64:415]; wave 1 zeroes R[:, 415:512].
__global__ __launch_bounds__(256) void embed_interact_kernel(
    const int* __restrict__ idx, const float* __restrict__ emb,
    __hip_bfloat16* __restrict__ R)
{
    __shared__ __align__(16) short T[32 * 64];
    __shared__ int sidx[TT * LL];
    const int b = blockIdx.x;
    const int tid = threadIdx.x;
    const int lane = tid & 63;
    const int w = tid >> 6;

    if (tid < TT * LL) sidx[tid] = idx[(size_t)b * (TT * LL) + tid];
    // zero pad rows 27..31
    for (int i = tid; i < 5 * 64; i += 256) {
        int r = 27 + (i >> 6), l = i & 63;
        *(short*)((char*)T + r * 128 + ((l * 2) ^ ((r & 7) << 4))) = 0;
    }
    __syncthreads();

    // phase 1: issue all row loads into registers (28 outstanding/lane), then sum
    float v[7][4];
#pragma unroll
    for (int rr = 0; rr < 7; rr++) {
        const int r = rr * 4 + w;
        if (r == 0) {
            v[rr][0] = __bfloat162float(R[(size_t)b * RSTR + lane]);
            v[rr][1] = 0.f; v[rr][2] = 0.f; v[rr][3] = 0.f;
        } else if (r < 27) {
            const int t = r - 1;
            const float* tab = emb + (size_t)t * NROWS * MM + lane;
#pragma unroll
            for (int l = 0; l < LL; l++)
                v[rr][l] = tab[(size_t)sidx[t * LL + l] * MM];
        }
    }
#pragma unroll
    for (int rr = 0; rr < 7; rr++) {
        const int r = rr * 4 + w;
        if (r < 27) {
            float s = v[rr][0] + v[rr][1] + v[rr][2] + v[rr][3];
            __hip_bfloat16 hv = __float2bfloat16(s);
            *(short*)((char*)T + r * 128 + ((lane * 2) ^ ((r & 7) << 4))) = *(short*)&hv;
        }
    }
    __syncthreads();

    __hip_bfloat16* Rb = R + (size_t)b * RSTR;
    if (w == 1) {
        Rb[415 + lane] = __float2bfloat16(0.f);
        if (lane < 33) Rb[479 + lane] = __float2bfloat16(0.f);
    }
    if (w == 0) {
        f32x16 acc = {};
#pragma unroll
        for (int m = 0; m < 4; m++) {
            int byteoff = (lane & 31) * 128 +
                          ((m * 32 + (lane >> 5) * 16) ^ ((lane & 7) << 4));
            bf16x8 f = *(const bf16x8*)((const char*)T + byteoff);
            acc = __builtin_amdgcn_mfma_f32_32x32x16_bf16(f, f, acc, 0, 0, 0);
        }
        const int col = lane & 31;
#pragma unroll
        for (int q = 0; q < 4; q++) {
#pragma unroll
            for (int j = 0; j < 4; j++) {
                int row = j + 8 * q + 4 * (lane >> 5);
                if (row < 27 && col < row)
                    Rb[64 + row * (row - 1) / 2 + col] = __float2bfloat16(acc[q * 4 + j]);
            }
        }
    }
}

// ---------------- top layer 2: (4096,256) bf16 -> (4096,1), sigmoid ----------------
__global__ __launch_bounds__(256) void top2_kernel(
    const __hip_bfloat16* __restrict__ h, const float* __restrict__ W,
    const float* __restrict__ bias, float* __restrict__ out)
{
    __shared__ float ws[256];
    int tid = threadIdx.x;
    ws[tid] = W[tid];
    __syncthreads();
    int b = blockIdx.x * 4 + (tid >> 6);
    int lane = tid & 63;
    const unsigned short* hb = (const unsigned short*)(h + (size_t)b * 256);
    ushort4 hv = *(const ushort4*)&hb[lane * 4];
    float4 wv = *(const float4*)&ws[lane * 4];
    float s = bu2f(hv.x) * wv.x + bu2f(hv.y) * wv.y + bu2f(hv.z) * wv.z + bu2f(hv.w) * wv.w;
#pragma unroll
    for (int off = 32; off >= 1; off >>= 1)
        s += __shfl_xor(s, off, 64);
    if (lane == 0) {
        float v = s + bias[0];
        out[b] = 1.0f / (1.0f + expf(-v));
    }
}

// ---------------- launch ----------------
extern "C" void kernel_launch(void* const* d_in, const int* in_sizes, int n_in,
                              void* d_out, int out_size, void* d_ws, size_t ws_size,
                              hipStream_t stream) {
    const float* dense = (const float*)d_in[0];
    const int*   sidx  = (const int*)d_in[1];
    const float* emb   = (const float*)d_in[2];
    const float* bw0   = (const float*)d_in[3];
    const float* bb0   = (const float*)d_in[4];
    const float* bw1   = (const float*)d_in[5];
    const float* bb1   = (const float*)d_in[6];
    const float* bw2   = (const float*)d_in[7];
    const float* bb2   = (const float*)d_in[8];
    const float* tw0   = (const float*)d_in[9];
    const float* tb0   = (const float*)d_in[10];
    const float* tw1   = (const float*)d_in[11];
    const float* tb1   = (const float*)d_in[12];
    const float* tw2   = (const float*)d_in[13];
    const float* tb2   = (const float*)d_in[14];
    float* out = (float*)d_out;

    char* wsb = (char*)d_ws;
    __hip_bfloat16* x1   = (__hip_bfloat16*)(wsb);                 // 4096x512
    __hip_bfloat16* x2   = (__hip_bfloat16*)(wsb + (4u << 20));    // 4096x256
    __hip_bfloat16* R    = (__hip_bfloat16*)(wsb + (8u << 20));    // 4096x512
    __hip_bfloat16* h1   = (__hip_bfloat16*)(wsb + (12u << 20));   // 4096x512
    __hip_bfloat16* h2   = (__hip_bfloat16*)(wsb + (16u << 20));   // 4096x256
    __hip_bfloat16* bw1b = (__hip_bfloat16*)(wsb + (18u << 20));   // 256x512
    __hip_bfloat16* bw2b = bw1b + 131072;                          // 64x256
    __hip_bfloat16* tw0b = bw2b + 16384;                           // 512x512
    __hip_bfloat16* tw1b = tw0b + 262144;                          // 256x512

    // 1. weight conversion + bottom layer 0
    prep_kernel<<<CONV_BLOCKS + BATCH, 256, 0, stream>>>(
        dense, bw0, bb0, bw1, bw2, tw0, tw1, x1, bw1b, bw2b, tw0b, tw1b);

    // 2. bottom layer 1: x1 (4096,512) -> x2 (4096,256)   [256 blocks -> fullk]
    gemm_fullk<512, 1><<<dim3(64, 4), 256, 0, stream>>>(x1, bw1b, bb1, x2, 256);

    // 3. bottom layer 2: x2 (4096,256) -> R[:, 0:64]      [64 blocks -> fullk]
    gemm_fullk<256, 1><<<dim3(64, 1), 256, 0, stream>>>(x2, bw2b, bb2, R, RSTR);

    // 4. fused embedding + Gram interaction -> R[:, 64:512]
    embed_interact_kernel<<<BATCH, 256, 0, stream>>>(sidx, emb, R);

    // 5. top layer 0: R (4096,512) -> h1 (4096,512)       [512 blocks -> db, 2/CU]
    gemm_db<512, 1><<<dim3(64, 8), 256, 0, stream>>>(R, tw0b, tb0, h1, 512);

    // 6. top layer 1: h1 (4096,512) -> h2 (4096,256)      [256 blocks -> fullk]
    gemm_fullk<512, 1><<<dim3(64, 4), 256, 0, stream>>>(h1, tw1b, tb1, h2, 256);

    // 7. top layer 2: h2 -> out, sigmoid
    top2_kernel<<<BATCH / 4, 256, 0, stream>>>(h2, tw2, tb2, out);
}